// Round 1
// baseline (45.257 us; speedup 1.0000x reference)
//
#include <hip/hip_runtime.h>

// Burgers PDE step: out = d*delta_u - adv
//   delta_u = (U[i-1] - 2U[i] + U[i+1]) / dx^2
//   adv     = max(u,0)*(U[i]-U[i-1])/dx + min(u,0)*(U[i+1]-U[i])/dx
//   d       = sigmoid(d_org) * 0.01
// U padded with Dirichlet bc: U[-1]=bc[0], U[N]=bc[1].
// Memory-bound streaming stencil: float4 vectorized, halo from cache.

#define INV_DX  100.0f     // 1/0.01
#define INV_DX2 10000.0f   // 1/0.01^2

__global__ __launch_bounds__(256) void burgers_kernel(
    const float* __restrict__ u,
    const float* __restrict__ bc,
    const float* __restrict__ d_org,
    float* __restrict__ out,
    int n)
{
    const int quad = blockIdx.x * blockDim.x + threadIdx.x;  // group of 4 elems
    const int base = quad * 4;
    if (base >= n) return;

    const float d = 0.01f / (1.0f + expf(-d_org[0]));

    if (base + 4 <= n) {
        // main vectorized path
        const float4 v = *reinterpret_cast<const float4*>(u + base);
        const float left  = (base == 0)     ? bc[0] : u[base - 1];
        const float right = (base + 4 == n) ? bc[1] : u[base + 4];

        const float c[6] = {left, v.x, v.y, v.z, v.w, right};
        float4 o;
        float* op = &o.x;
        #pragma unroll
        for (int j = 0; j < 4; ++j) {
            const float l = c[j], m = c[j + 1], r = c[j + 2];
            const float delta = (l - 2.0f * m + r) * INV_DX2;
            const float advl  = (m - l) * INV_DX;
            const float advr  = (r - m) * INV_DX;
            const float adv   = fmaxf(m, 0.0f) * advl + fminf(m, 0.0f) * advr;
            op[j] = d * delta - adv;
        }
        *reinterpret_cast<float4*>(out + base) = o;
    } else {
        // scalar tail (not hit for N=2^25, defensive)
        for (int i = base; i < n; ++i) {
            const float m = u[i];
            const float l = (i == 0)     ? bc[0] : u[i - 1];
            const float r = (i == n - 1) ? bc[1] : u[i + 1];
            const float delta = (l - 2.0f * m + r) * INV_DX2;
            const float advl  = (m - l) * INV_DX;
            const float advr  = (r - m) * INV_DX;
            const float adv   = fmaxf(m, 0.0f) * advl + fminf(m, 0.0f) * advr;
            out[i] = d * delta - adv;
        }
    }
}

extern "C" void kernel_launch(void* const* d_in, const int* in_sizes, int n_in,
                              void* d_out, int out_size, void* d_ws, size_t ws_size,
                              hipStream_t stream) {
    const float* u     = (const float*)d_in[0];  // state [1,1,N]
    const float* bc    = (const float*)d_in[1];  // [1,1,2]
    const float* d_org = (const float*)d_in[2];  // scalar
    float* out = (float*)d_out;

    const int n = in_sizes[0];
    const int quads = (n + 3) / 4;
    const int threads = 256;
    const int blocks = (quads + threads - 1) / threads;

    burgers_kernel<<<blocks, threads, 0, stream>>>(u, bc, d_org, out, n);
}